// Round 22
// baseline (52.842 us; speedup 1.0000x reference)
//
#include <hip/hip_runtime.h>
#include <math.h>

// Problem constants: B=1, S=256, HID=1024, H=16, KV=8, D=64, N_REP=2
#define SCALE 0.125f   // 1/sqrt(64)
#define LOG2E 1.44269504088896340736f

typedef short short8 __attribute__((ext_vector_type(8)));
typedef float floatx4 __attribute__((ext_vector_type(4)));

static __device__ __forceinline__ ushort f2bf(float x) {
  uint32_t b = __float_as_uint(x);
  uint32_t r = (b + 0x7FFFu + ((b >> 16) & 1u)) >> 16;   // RNE
  return (ushort)r;
}
static __device__ __forceinline__ float bf2f(ushort u) {
  return __uint_as_float(((uint32_t)u) << 16);
}

// ---------------------------------------------------------------------------
// MFMA bf16 GEMM 1: X(256x1024) @ [Wq|Wk|Wv](1024x2048) -> QKV partials.
// K-split 4. grid = 512 (4 ksplit * 128 tiles), block = 256. (verified R8/R13)
// ---------------------------------------------------------------------------
__global__ __launch_bounds__(256) void gemm_qkv_kernel(
    const float* __restrict__ X, const float* __restrict__ Wq,
    const float* __restrict__ Wk, const float* __restrict__ Wv,
    float* __restrict__ Cp) {
  __shared__ ushort As[4096];
  __shared__ ushort Bs[4096];
  char* Asc = (char*)As;
  char* Bsc = (char*)Bs;
  const int bx = blockIdx.x;
  const int ks = bx >> 7;            // 0..3
  const int tile = bx & 127;         // 4 m-tiles x 32 n-tiles
  const int tile_n = tile & 31, tile_m = tile >> 5;
  const int n0 = tile_n * 64, m0 = tile_m * 64;
  const float* Bp; int ldb, bc0;
  if (n0 < 1024)      { Bp = Wq; ldb = 1024; bc0 = n0; }
  else if (n0 < 1536) { Bp = Wk; ldb = 512;  bc0 = n0 - 1024; }
  else                { Bp = Wv; ldb = 512;  bc0 = n0 - 1536; }
  const int t = threadIdx.x;
  const int arow = t >> 4, acg = t & 15;
  const int bng = t & 15;
  const int kbeg = ks * 256;
  float4 ra[4], rb0[2], rb1[2];
  auto LOAD = [&](int k0) {
    #pragma unroll
    for (int i = 0; i < 4; ++i)
      ra[i] = *reinterpret_cast<const float4*>(X + (size_t)(m0 + arow + 16 * i) * 1024 + k0 + acg * 4);
    #pragma unroll
    for (int i = 0; i < 2; ++i) {
      int k = 2 * ((t >> 4) + 16 * i);
      rb0[i] = *reinterpret_cast<const float4*>(Bp + (size_t)(k0 + k) * ldb + bc0 + bng * 4);
      rb1[i] = *reinterpret_cast<const float4*>(Bp + (size_t)(k0 + k + 1) * ldb + bc0 + bng * 4);
    }
  };
  LOAD(kbeg);
  const int wid = t >> 6, wr = wid >> 1, wc = wid & 1, lane = t & 63;
  const int lr = lane & 15, lk = lane >> 4;
  const int sw = (lr & 7) << 4;
  floatx4 acc[2][2];
  #pragma unroll
  for (int mt = 0; mt < 2; ++mt)
    #pragma unroll
    for (int nt = 0; nt < 2; ++nt)
      acc[mt][nt] = (floatx4){0.f, 0.f, 0.f, 0.f};
  for (int kt = 0; kt < 4; ++kt) {
    #pragma unroll
    for (int i = 0; i < 4; ++i) {
      int row = arow + 16 * i;
      ushort4 w;
      w.x = f2bf(ra[i].x); w.y = f2bf(ra[i].y); w.z = f2bf(ra[i].z); w.w = f2bf(ra[i].w);
      *reinterpret_cast<ushort4*>(Asc + row * 128 + ((acg * 8) ^ ((row & 7) << 4))) = w;
    }
    #pragma unroll
    for (int i = 0; i < 2; ++i) {
      int k = 2 * ((t >> 4) + 16 * i);
      const float* p0 = (const float*)&rb0[i];
      const float* p1 = (const float*)&rb1[i];
      #pragma unroll
      for (int j = 0; j < 4; ++j) {
        int n = bng * 4 + j;
        uint32_t v = (uint32_t)f2bf(p0[j]) | ((uint32_t)f2bf(p1[j]) << 16);
        *reinterpret_cast<uint32_t*>(Bsc + n * 128 + ((k * 2) ^ ((n & 7) << 4))) = v;
      }
    }
    __syncthreads();
    if (kt + 1 < 4) LOAD(kbeg + 64 * (kt + 1));
    #pragma unroll
    for (int kc = 0; kc < 2; ++kc) {
      short8 af[2], bf[2];
      #pragma unroll
      for (int mt = 0; mt < 2; ++mt)
        af[mt] = *reinterpret_cast<const short8*>(
            Asc + (wr * 32 + mt * 16 + lr) * 128 + ((kc * 64 + lk * 16) ^ sw));
      #pragma unroll
      for (int nt = 0; nt < 2; ++nt)
        bf[nt] = *reinterpret_cast<const short8*>(
            Bsc + (wc * 32 + nt * 16 + lr) * 128 + ((kc * 64 + lk * 16) ^ sw));
      #pragma unroll
      for (int mt = 0; mt < 2; ++mt)
        #pragma unroll
        for (int nt = 0; nt < 2; ++nt)
          acc[mt][nt] = __builtin_amdgcn_mfma_f32_16x16x32_bf16(af[mt], bf[nt], acc[mt][nt], 0, 0, 0);
    }
    __syncthreads();
  }
  float* Co = Cp + (size_t)ks * 524288;
  #pragma unroll
  for (int mt = 0; mt < 2; ++mt)
    #pragma unroll
    for (int nt = 0; nt < 2; ++nt)
      #pragma unroll
      for (int r = 0; r < 4; ++r) {
        int row = wr * 32 + mt * 16 + lk * 4 + r;
        int col = wc * 32 + nt * 16 + lr;
        Co[(size_t)(m0 + row) * 2048 + n0 + col] = acc[mt][nt][r];
      }
}

// ---------------------------------------------------------------------------
// Reduce the 4 QKV partials + RoPE on q/k heads. grid = 1280, block = 256.
// ---------------------------------------------------------------------------
__global__ __launch_bounds__(256) void rope_reduce_kernel(
    const float* __restrict__ Cp, float* __restrict__ QKV,
    const float* __restrict__ cs, const float* __restrict__ sn) {
  int idx = blockIdx.x * 256 + threadIdx.x;
  const float* P0 = Cp;
  const float* P1 = Cp + 524288;
  const float* P2p = Cp + 1048576;
  const float* P3 = Cp + 1572864;
  if (idx < 196608) {                 // 256 s * 24 heads * 32 pairs
    int dp = idx & 31;
    int head = (idx >> 5) % 24;       // 0..15 q heads, 16..23 k heads
    int s = idx / 768;
    int base = s * 2048 + head * 64;
    int a1 = base + dp, a2 = base + dp + 32;
    float x1 = P0[a1] + P1[a1] + P2p[a1] + P3[a1];
    float x2 = P0[a2] + P1[a2] + P2p[a2] + P3[a2];
    float c1 = cs[s * 64 + dp],      s1v = sn[s * 64 + dp];
    float c2 = cs[s * 64 + dp + 32], s2v = sn[s * 64 + dp + 32];
    QKV[a1] = x1 * c1 - x2 * s1v;   // q' = q*cos + rot_half(q)*sin
    QKV[a2] = x2 * c2 + x1 * s2v;
  } else {
    int i2 = idx - 196608;            // 131072 v elements
    int s = i2 >> 9, c = 1536 + (i2 & 511);
    int a = s * 2048 + c;
    QKV[a] = P0[a] + P1[a] + P2p[a] + P3[a];
  }
}

// ---------------------------------------------------------------------------
// FUSED QK^T + softmax + p_diff + PV, v5: OCCUPANCY FIX.
// R18 evidence: grid 256 = 1 block/CU (grid-limited!), 19% issue efficiency.
// Now: grid 512 (8 g x 64 u), block 512 (8 waves, ONE row each: 8 rows =
// 2h x {2u,2u+1,mirrors}), LDS 74KB -> 2 blocks/CU = 4 waves/SIMD (2x TLP).
// Scalar k from swizzled ksh (conflict-free), v from linear vsh (immediate-
// offset reads), aw|ep packed bf16 broadcast. Sp/P2p hoisted (lane-invariant
// -> per-row shuffle reduce). vpart dropped (tail sums |attn_out|).
// ---------------------------------------------------------------------------
__global__ __launch_bounds__(512) void pdiff_fused_kernel(
    const float* __restrict__ QKV, float* __restrict__ pOut,
    float* __restrict__ qkpart, float* __restrict__ attn_out) {
  __shared__ ushort ksh[16384];       // 32KB swizzled [t][d] bf16
  __shared__ ushort vsh[16384];       // 32KB linear  [t][d] bf16
  __shared__ ushort qsh[1024];        // 2KB swizzled 16 row-slots (8 valid)
  __shared__ uint32_t awep[8][258];   // 8.06KB: aw bf16 lo | ep bf16 hi
  char* kshc = (char*)ksh;
  char* qshc = (char*)qsh;
  const int g = blockIdx.x >> 6;      // 0..7
  const int u = blockIdx.x & 63;      // 0..63
  const int t = threadIdx.x;
  // stage k (swizzled) + v (linear)
  #pragma unroll
  for (int i = 0; i < 8; ++i) {
    int fi = t + i * 512;              // 4096 float4 slots
    int tt = fi >> 4, c = (fi & 15) * 4;
    float4 kv = *reinterpret_cast<const float4*>(QKV + (size_t)tt * 2048 + 1024 + g * 64 + c);
    float4 vv = *reinterpret_cast<const float4*>(QKV + (size_t)tt * 2048 + 1536 + g * 64 + c);
    ushort4 wk, wv;
    wk.x = f2bf(kv.x); wk.y = f2bf(kv.y); wk.z = f2bf(kv.z); wk.w = f2bf(kv.w);
    wv.x = f2bf(vv.x); wv.y = f2bf(vv.y); wv.z = f2bf(vv.z); wv.w = f2bf(vv.w);
    *reinterpret_cast<ushort4*>(kshc + tt * 128 + ((c * 2) ^ ((tt & 7) << 4))) = wk;
    *reinterpret_cast<ushort4*>(&vsh[tt * 64 + c]) = wv;
  }
  { // stage 16 q row-slots (8 valid, 8 zero): a = pr*4 + mr*2 + jo
    int a = t >> 5;                    // 0..15
    int c = (t & 31) * 2;              // 0..62
    uint32_t pk = 0;
    if (a < 8) {
      int pr = a >> 2, mr = (a >> 1) & 1, jo = a & 1;
      int s = mr ? 255 - (2 * u + jo) : 2 * u + jo;
      int hh = 2 * g + pr;
      float2 qv = *reinterpret_cast<const float2*>(QKV + (size_t)s * 2048 + hh * 64 + c);
      pk = (uint32_t)f2bf(qv.x) | ((uint32_t)f2bf(qv.y) << 16);
    }
    *reinterpret_cast<uint32_t*>(qshc + a * 128 + ((c * 2) ^ ((a & 7) << 4))) = pk;
  }
  __syncthreads();
  const int w = t >> 6, lane = t & 63;
  const int lr = lane & 15, lk = lane >> 4;
  const int sw = (lr & 7) << 4;
  const float AWS = SCALE * SCALE * LOG2E;
  // QK^T: 16 col-tiles, 2 per wave; write awep (aw + ep, mask baked in)
  #pragma unroll
  for (int q2 = 0; q2 < 2; ++q2) {
    int nt = 2 * w + q2;
    floatx4 acc = (floatx4){0.f, 0.f, 0.f, 0.f};
    #pragma unroll
    for (int kc = 0; kc < 2; ++kc) {
      short8 af = *reinterpret_cast<const short8*>(
          qshc + lr * 128 + ((kc * 64 + lk * 16) ^ sw));
      int tt = nt * 16 + lr;
      short8 bf = *reinterpret_cast<const short8*>(
          kshc + tt * 128 + ((kc * 64 + lk * 16) ^ ((tt & 7) << 4)));
      acc = __builtin_amdgcn_mfma_f32_16x16x32_bf16(af, bf, acc, 0, 0, 0);
    }
    #pragma unroll
    for (int r = 0; r < 4; ++r) {
      int a = lk * 4 + r;
      if (a < 8) {
        int pr = a >> 2, mr = (a >> 1) & 1, jo = a & 1;
        int sa = mr ? 255 - (2 * u + jo) : 2 * u + jo;
        int tc = nt * 16 + lr;
        float aw = (tc <= sa) ? acc[r] * AWS : -1000.0f;
        float ep = __builtin_amdgcn_exp2f(8.0f * aw);
        awep[a][tc] = (uint32_t)f2bf(aw) | ((uint32_t)f2bf(ep) << 16);
      }
    }
  }
  __syncthreads();
  // each wave owns row a = w
  const int a = w;
  const int pr = a >> 2, mr = (a >> 1) & 1, jo = a & 1;
  const int h = 2 * g + pr;
  const int s = mr ? 255 - (2 * u + jo) : 2 * u + jo;
  const uint32_t* aerow = awep[a];
  // hoist Sp, P2p (lane-invariant): lane-parallel + shuffle reduce
  float sp = 0.f, p2 = 0.f;
  #pragma unroll
  for (int i = 0; i < 4; ++i) {
    float ep = bf2f((ushort)(aerow[lane + i * 64] >> 16));
    sp += ep;
    p2 = fmaf(ep, ep, p2);
  }
  #pragma unroll
  for (int off = 32; off; off >>= 1) {
    sp += __shfl_xor(sp, off);
    p2 += __shfl_xor(p2, off);
  }
  const float cd2 = (SCALE * LOG2E) * QKV[(size_t)s * 2048 + h * 64 + lane];
  float S1 = 0.f, S2 = 0.f, S3p = 0.f, AVp = 0.f;
  const int kbase = 2 * lane;
  const int nt8 = (s + 8) & ~7;        // masked region contributes exact 0
  #pragma unroll 8
  for (int tt = 0; tt < nt8; ++tt) {
    float kf = bf2f(*reinterpret_cast<const ushort*>(
        kshc + tt * 128 + (kbase ^ ((tt & 7) << 4))));
    float vf = bf2f(vsh[tt * 64 + lane]);
    uint32_t ae = aerow[tt];
    float aw = bf2f((ushort)ae);
    float ep = bf2f((ushort)(ae >> 16));
    float e = __builtin_amdgcn_exp2f(fmaf(-cd2, kf, aw));
    S1 += e;
    S2  = fmaf(e, e, S2);
    S3p = fmaf(e, ep, S3p);
    AVp = fmaf(ep, vf, AVp);
  }
  float invS1 = 1.f / S1, invSp = 1.f / sp;
  float qk = S2 * invS1 * invS1 - 2.f * S3p * invS1 * invSp + p2 * invSp * invSp;
  float av = AVp * invSp;
  attn_out[(size_t)s * 1024 + h * 64 + lane] = av;
  size_t rowbase = ((size_t)h * 256 + s) * 256;
  #pragma unroll
  for (int i = 0; i < 4; ++i) {
    int tc = lane + i * 64;
    pOut[rowbase + tc] = bf2f((ushort)(aerow[tc] >> 16)) * invSp;  // masked->0
  }
  qkpart[((size_t)h * 256 + s) * 64 + lane] = qk;
}

// ---------------------------------------------------------------------------
// GEMM 2 + tail in ONE dispatch. Blocks 0..255: 32x32-tile FULL-K bf16 MFMA,
// direct write to out. Blocks 256..263: qk (sum over 256 s) / v/o importance
// (sum |attn_out| over s). grid = 264, block = 256.
// ---------------------------------------------------------------------------
__global__ __launch_bounds__(256) void gemm_o_tail_kernel(
    const float* __restrict__ A, const float* __restrict__ W,
    const float* __restrict__ qkpart, float* __restrict__ out,
    float* __restrict__ qkout, float* __restrict__ vout,
    float* __restrict__ oout) {
  __shared__ ushort As[2048];   // 32 rows x 64 k bf16, XOR swizzle
  __shared__ ushort Bs[2048];   // 32 n    x 64 k
  char* Asc = (char*)As;
  char* Bsc = (char*)Bs;
  const int b = blockIdx.x, t = threadIdx.x;
  if (b < 256) {
    const int tm = b >> 5, tn = b & 31;       // 8 m x 32 n tiles
    const int m0 = tm * 32, n0 = tn * 32;
    const int arow = t >> 3, aslot = t & 7;   // A: 32 rows x 16 slots
    const int kp = t >> 3, ng = t & 7;        // B: 32 kpairs x 8 ngroups
    float4 ra[2], rb0, rb1;
    auto LOAD = [&](int k0) {
      #pragma unroll
      for (int i = 0; i < 2; ++i)
        ra[i] = *reinterpret_cast<const float4*>(A + (size_t)(m0 + arow) * 1024 + k0 + (aslot + 8 * i) * 4);
      rb0 = *reinterpret_cast<const float4*>(W + (size_t)(k0 + 2 * kp) * 1024 + n0 + ng * 4);
      rb1 = *reinterpret_cast<const float4*>(W + (size_t)(k0 + 2 * kp + 1) * 1024 + n0 + ng * 4);
    };
    LOAD(0);
    const int wid = t >> 6, qm = wid >> 1, qn = wid & 1, lane = t & 63;
    const int lr = lane & 15, lk = lane >> 4;
    const int sw = (lr & 7) << 4;
    floatx4 acc = (floatx4){0.f, 0.f, 0.f, 0.f};
    for (int kt = 0; kt < 16; ++kt) {
      #pragma unroll
      for (int i = 0; i < 2; ++i) {
        int c = (aslot + 8 * i) * 4;
        ushort4 wv;
        wv.x = f2bf(ra[i].x); wv.y = f2bf(ra[i].y); wv.z = f2bf(ra[i].z); wv.w = f2bf(ra[i].w);
        *reinterpret_cast<ushort4*>(Asc + arow * 128 + ((c * 2) ^ ((arow & 7) << 4))) = wv;
      }
      {
        const float* p0 = (const float*)&rb0;
        const float* p1 = (const float*)&rb1;
        #pragma unroll
        for (int j = 0; j < 4; ++j) {
          int n = ng * 4 + j;
          uint32_t v = (uint32_t)f2bf(p0[j]) | ((uint32_t)f2bf(p1[j]) << 16);
          *reinterpret_cast<uint32_t*>(Bsc + n * 128 + ((kp * 4) ^ ((n & 7) << 4))) = v;
        }
      }
      __syncthreads();
      if (kt + 1 < 16) LOAD(64 * (kt + 1));
      #pragma unroll
      for (int kc = 0; kc < 2; ++kc) {
        short8 af = *reinterpret_cast<const short8*>(
            Asc + (qm * 16 + lr) * 128 + ((kc * 64 + lk * 16) ^ sw));
        short8 bf = *reinterpret_cast<const short8*>(
            Bsc + (qn * 16 + lr) * 128 + ((kc * 64 + lk * 16) ^ sw));
        acc = __builtin_amdgcn_mfma_f32_16x16x32_bf16(af, bf, acc, 0, 0, 0);
      }
      __syncthreads();
    }
    #pragma unroll
    for (int r = 0; r < 4; ++r) {
      int row = m0 + qm * 16 + lk * 4 + r;
      int col = n0 + qn * 16 + lr;
      out[(size_t)row * 1024 + col] = acc[r];
    }
  } else {
    int idx = (b - 256) * 256 + t;            // 0..2047
    if (idx < 1024) {
      int h = idx >> 6, d = idx & 63;
      float sum = 0.f;
      for (int j = 0; j < 256; ++j) sum += qkpart[((size_t)h * 256 + j) * 64 + d];
      qkout[idx] = sum;
    } else {
      int c = idx - 1024;
      float sum = 0.f;
      for (int s = 0; s < 256; ++s) sum += fabsf(A[(size_t)s * 1024 + c]);
      vout[c] = sum;
      oout[c] = sum;
    }
  }
}

// ---------------------------------------------------------------------------
extern "C" void kernel_launch(void* const* d_in, const int* in_sizes, int n_in,
                              void* d_out, int out_size, void* d_ws, size_t ws_size,
                              hipStream_t stream) {
  const float* X    = (const float*)d_in[0];   // hidden_states (1,256,1024)
  const float* cosp = (const float*)d_in[1];   // (1,256,64)
  const float* sinp = (const float*)d_in[2];   // (1,256,64)
  // d_in[3] attention_mask: causal, implemented analytically
  const float* Wq   = (const float*)d_in[4];   // (1024,1024)
  const float* Wk   = (const float*)d_in[5];   // (1024,512)
  const float* Wv   = (const float*)d_in[6];   // (1024,512)
  const float* Wo   = (const float*)d_in[7];   // (1024,1024)

  float* out  = (float*)d_out;                 // 262144
  float* pOut = out + 262144;                  // 1048576
  float* qki  = pOut + 1048576;                // 1024
  float* vi   = qki + 1024;                    // 1024
  float* oi   = vi + 1024;                     // 1024

  float* ws       = (float*)d_ws;
  float* QKV      = ws;                        // 524288 (s-major, 2048 cols: q|k|v)
  float* attn_out = ws + 524288;               // 262144
  float* qkpart   = ws + 786432;               // 262144 (per-row qk)
  float* scratch  = ws + 1048576;              // 2097152 (QKV partials x4)

  hipLaunchKernelGGL(gemm_qkv_kernel, dim3(512), dim3(256), 0, stream, X, Wq, Wk, Wv, scratch);
  hipLaunchKernelGGL(rope_reduce_kernel, dim3(1280), dim3(256), 0, stream, scratch, QKV, cosp, sinp);
  hipLaunchKernelGGL(pdiff_fused_kernel, dim3(512), dim3(512), 0, stream, QKV, pOut, qkpart, attn_out);
  hipLaunchKernelGGL(gemm_o_tail_kernel, dim3(264), dim3(256), 0, stream, attn_out, Wo, qkpart, out, qki, vi, oi);
}

// Round 23
// 43.117 us; speedup vs baseline: 1.2255x; 1.2255x over previous
//
#include <hip/hip_runtime.h>
#include <math.h>

// Problem constants: B=1, S=256, HID=1024, H=16, KV=8, D=64, N_REP=2
#define SCALE 0.125f   // 1/sqrt(64)
#define LOG2E 1.44269504088896340736f

typedef short short8 __attribute__((ext_vector_type(8)));
typedef float floatx4 __attribute__((ext_vector_type(4)));

static __device__ __forceinline__ ushort f2bf(float x) {
  uint32_t b = __float_as_uint(x);
  uint32_t r = (b + 0x7FFFu + ((b >> 16) & 1u)) >> 16;   // RNE
  return (ushort)r;
}
static __device__ __forceinline__ float bf2f(ushort u) {
  return __uint_as_float(((uint32_t)u) << 16);
}

// ---------------------------------------------------------------------------
// MFMA bf16 GEMM 1: X(256x1024) @ [Wq|Wk|Wv](1024x2048) -> QKV partials.
// K-split 4. grid = 512 (4 ksplit * 128 tiles), block = 256. (verified R8/R13)
// ---------------------------------------------------------------------------
__global__ __launch_bounds__(256) void gemm_qkv_kernel(
    const float* __restrict__ X, const float* __restrict__ Wq,
    const float* __restrict__ Wk, const float* __restrict__ Wv,
    float* __restrict__ Cp) {
  __shared__ ushort As[4096];
  __shared__ ushort Bs[4096];
  char* Asc = (char*)As;
  char* Bsc = (char*)Bs;
  const int bx = blockIdx.x;
  const int ks = bx >> 7;            // 0..3
  const int tile = bx & 127;         // 4 m-tiles x 32 n-tiles
  const int tile_n = tile & 31, tile_m = tile >> 5;
  const int n0 = tile_n * 64, m0 = tile_m * 64;
  const float* Bp; int ldb, bc0;
  if (n0 < 1024)      { Bp = Wq; ldb = 1024; bc0 = n0; }
  else if (n0 < 1536) { Bp = Wk; ldb = 512;  bc0 = n0 - 1024; }
  else                { Bp = Wv; ldb = 512;  bc0 = n0 - 1536; }
  const int t = threadIdx.x;
  const int arow = t >> 4, acg = t & 15;
  const int bng = t & 15;
  const int kbeg = ks * 256;
  float4 ra[4], rb0[2], rb1[2];
  auto LOAD = [&](int k0) {
    #pragma unroll
    for (int i = 0; i < 4; ++i)
      ra[i] = *reinterpret_cast<const float4*>(X + (size_t)(m0 + arow + 16 * i) * 1024 + k0 + acg * 4);
    #pragma unroll
    for (int i = 0; i < 2; ++i) {
      int k = 2 * ((t >> 4) + 16 * i);
      rb0[i] = *reinterpret_cast<const float4*>(Bp + (size_t)(k0 + k) * ldb + bc0 + bng * 4);
      rb1[i] = *reinterpret_cast<const float4*>(Bp + (size_t)(k0 + k + 1) * ldb + bc0 + bng * 4);
    }
  };
  LOAD(kbeg);
  const int wid = t >> 6, wr = wid >> 1, wc = wid & 1, lane = t & 63;
  const int lr = lane & 15, lk = lane >> 4;
  const int sw = (lr & 7) << 4;
  floatx4 acc[2][2];
  #pragma unroll
  for (int mt = 0; mt < 2; ++mt)
    #pragma unroll
    for (int nt = 0; nt < 2; ++nt)
      acc[mt][nt] = (floatx4){0.f, 0.f, 0.f, 0.f};
  for (int kt = 0; kt < 4; ++kt) {
    #pragma unroll
    for (int i = 0; i < 4; ++i) {
      int row = arow + 16 * i;
      ushort4 w;
      w.x = f2bf(ra[i].x); w.y = f2bf(ra[i].y); w.z = f2bf(ra[i].z); w.w = f2bf(ra[i].w);
      *reinterpret_cast<ushort4*>(Asc + row * 128 + ((acg * 8) ^ ((row & 7) << 4))) = w;
    }
    #pragma unroll
    for (int i = 0; i < 2; ++i) {
      int k = 2 * ((t >> 4) + 16 * i);
      const float* p0 = (const float*)&rb0[i];
      const float* p1 = (const float*)&rb1[i];
      #pragma unroll
      for (int j = 0; j < 4; ++j) {
        int n = bng * 4 + j;
        uint32_t v = (uint32_t)f2bf(p0[j]) | ((uint32_t)f2bf(p1[j]) << 16);
        *reinterpret_cast<uint32_t*>(Bsc + n * 128 + ((k * 2) ^ ((n & 7) << 4))) = v;
      }
    }
    __syncthreads();
    if (kt + 1 < 4) LOAD(kbeg + 64 * (kt + 1));
    #pragma unroll
    for (int kc = 0; kc < 2; ++kc) {
      short8 af[2], bf[2];
      #pragma unroll
      for (int mt = 0; mt < 2; ++mt)
        af[mt] = *reinterpret_cast<const short8*>(
            Asc + (wr * 32 + mt * 16 + lr) * 128 + ((kc * 64 + lk * 16) ^ sw));
      #pragma unroll
      for (int nt = 0; nt < 2; ++nt)
        bf[nt] = *reinterpret_cast<const short8*>(
            Bsc + (wc * 32 + nt * 16 + lr) * 128 + ((kc * 64 + lk * 16) ^ sw));
      #pragma unroll
      for (int mt = 0; mt < 2; ++mt)
        #pragma unroll
        for (int nt = 0; nt < 2; ++nt)
          acc[mt][nt] = __builtin_amdgcn_mfma_f32_16x16x32_bf16(af[mt], bf[nt], acc[mt][nt], 0, 0, 0);
    }
    __syncthreads();
  }
  float* Co = Cp + (size_t)ks * 524288;
  #pragma unroll
  for (int mt = 0; mt < 2; ++mt)
    #pragma unroll
    for (int nt = 0; nt < 2; ++nt)
      #pragma unroll
      for (int r = 0; r < 4; ++r) {
        int row = wr * 32 + mt * 16 + lk * 4 + r;
        int col = wc * 32 + nt * 16 + lr;
        Co[(size_t)(m0 + row) * 2048 + n0 + col] = acc[mt][nt][r];
      }
}

// ---------------------------------------------------------------------------
// Reduce the 4 QKV partials + RoPE on q/k heads. grid = 1280, block = 256.
// ---------------------------------------------------------------------------
__global__ __launch_bounds__(256) void rope_reduce_kernel(
    const float* __restrict__ Cp, float* __restrict__ QKV,
    const float* __restrict__ cs, const float* __restrict__ sn) {
  int idx = blockIdx.x * 256 + threadIdx.x;
  const float* P0 = Cp;
  const float* P1 = Cp + 524288;
  const float* P2p = Cp + 1048576;
  const float* P3 = Cp + 1572864;
  if (idx < 196608) {                 // 256 s * 24 heads * 32 pairs
    int dp = idx & 31;
    int head = (idx >> 5) % 24;       // 0..15 q heads, 16..23 k heads
    int s = idx / 768;
    int base = s * 2048 + head * 64;
    int a1 = base + dp, a2 = base + dp + 32;
    float x1 = P0[a1] + P1[a1] + P2p[a1] + P3[a1];
    float x2 = P0[a2] + P1[a2] + P2p[a2] + P3[a2];
    float c1 = cs[s * 64 + dp],      s1v = sn[s * 64 + dp];
    float c2 = cs[s * 64 + dp + 32], s2v = sn[s * 64 + dp + 32];
    QKV[a1] = x1 * c1 - x2 * s1v;   // q' = q*cos + rot_half(q)*sin
    QKV[a2] = x2 * c2 + x1 * s2v;
  } else {
    int i2 = idx - 196608;            // 131072 v elements
    int s = i2 >> 9, c = 1536 + (i2 & 511);
    int a = s * 2048 + c;
    QKV[a] = P0[a] + P1[a] + P2p[a] + P3[a];
  }
}

// ---------------------------------------------------------------------------
// FUSED QK^T + softmax + p_diff + PV, v6: R20 loop body + 4 waves/SIMD.
// grid 256 (1 block/CU, staging unchanged from R20), block 1024 = 16 waves,
// ONE row per wave (16 rows = 2h x {4u..4u+3, mirrors}). LDS 123KB, 1
// block/CU, 16 waves/CU = 4/SIMD (2x R20's TLP). t-loop body byte-identical
// to R20: kvT stride-258 b64 pairs (2-way alias, free), broadcast fp32 ep /
// bf16 aw, native v_exp, causal mask baked in.
// ---------------------------------------------------------------------------
__global__ __launch_bounds__(1024) void pdiff_fused_kernel(
    const float* __restrict__ QKV, float* __restrict__ pOut,
    float* __restrict__ qkpart, float* __restrict__ attn_out) {
  __shared__ ushort ksh[16384];       // 32KB swizzled [t][d] bf16 (MFMA B)
  __shared__ uint32_t kvT[64 * 258];  // 64.5KB transposed [d][t]: k lo | v hi
  __shared__ ushort qsh[1024];        // 2KB  swizzled [a][d] bf16 (16 rows)
  __shared__ ushort awsh[16][264];    // 8.25KB bf16 (scale^2*log2e*qk, masked)
  __shared__ float  epsh[16][260];    // 16.25KB fp32 2^(8*aw) per row
  char* kshc = (char*)ksh;
  char* qshc = (char*)qsh;
  const int g = blockIdx.x >> 5;
  const int u = blockIdx.x & 31;
  const int t = threadIdx.x;
  // stage k (swizzled, for MFMA) + kvT (transposed packed, for t-loop)
  #pragma unroll
  for (int i = 0; i < 4; ++i) {
    int fi = t + i * 1024;             // 4096 float4 slots
    int tt = fi >> 4, c = (fi & 15) * 4;
    float4 kv = *reinterpret_cast<const float4*>(QKV + (size_t)tt * 2048 + 1024 + g * 64 + c);
    float4 vv = *reinterpret_cast<const float4*>(QKV + (size_t)tt * 2048 + 1536 + g * 64 + c);
    ushort4 wk;
    wk.x = f2bf(kv.x); wk.y = f2bf(kv.y); wk.z = f2bf(kv.z); wk.w = f2bf(kv.w);
    *reinterpret_cast<ushort4*>(kshc + tt * 128 + ((c * 2) ^ ((tt & 7) << 4))) = wk;
    kvT[(c + 0) * 258 + tt] = (uint32_t)wk.x | ((uint32_t)f2bf(vv.x) << 16);
    kvT[(c + 1) * 258 + tt] = (uint32_t)wk.y | ((uint32_t)f2bf(vv.y) << 16);
    kvT[(c + 2) * 258 + tt] = (uint32_t)wk.z | ((uint32_t)f2bf(vv.z) << 16);
    kvT[(c + 3) * 258 + tt] = (uint32_t)wk.w | ((uint32_t)f2bf(vv.w) << 16);
  }
  if (t < 512) { // stage the 16 q rows: a = pr*8 + mr*4 + jo
    int a = t >> 5;                    // 0..15
    int c = (t & 31) * 2;              // 0..62
    int pr = a >> 3, mr = (a >> 2) & 1, jo = a & 3;
    int s = mr ? 255 - (4 * u + jo) : 4 * u + jo;
    int hh = 2 * g + pr;
    float2 qv = *reinterpret_cast<const float2*>(QKV + (size_t)s * 2048 + hh * 64 + c);
    uint32_t pk = (uint32_t)f2bf(qv.x) | ((uint32_t)f2bf(qv.y) << 16);
    *reinterpret_cast<uint32_t*>(qshc + a * 128 + ((c * 2) ^ ((a & 7) << 4))) = pk;
  }
  __syncthreads();
  const int w = t >> 6, lane = t & 63;
  const int lr = lane & 15, lk = lane >> 4;
  const int sw = (lr & 7) << 4;
  const float AWS = SCALE * SCALE * LOG2E;
  // QK^T: 16 col-tiles, ONE per wave; write awsh with causal mask baked in
  {
    int nt = w;
    floatx4 acc = (floatx4){0.f, 0.f, 0.f, 0.f};
    #pragma unroll
    for (int kc = 0; kc < 2; ++kc) {
      short8 af = *reinterpret_cast<const short8*>(
          qshc + lr * 128 + ((kc * 64 + lk * 16) ^ sw));
      int tt = nt * 16 + lr;
      short8 bf = *reinterpret_cast<const short8*>(
          kshc + tt * 128 + ((kc * 64 + lk * 16) ^ ((tt & 7) << 4)));
      acc = __builtin_amdgcn_mfma_f32_16x16x32_bf16(af, bf, acc, 0, 0, 0);
    }
    #pragma unroll
    for (int r = 0; r < 4; ++r) {
      int a = lk * 4 + r;
      int pr = a >> 3, mr = (a >> 2) & 1, jo = a & 3;
      int sa = mr ? 255 - (4 * u + jo) : 4 * u + jo;
      int tc = nt * 16 + lr;
      awsh[a][tc] = f2bf((tc <= sa) ? acc[r] * AWS : -1000.0f);
    }
  }
  __syncthreads();
  // wave w owns row a = w
  const int a = w;
  const int pr = a >> 3, mr = (a >> 2) & 1, jo = a & 3;
  const int h = 2 * g + pr;
  const int s = mr ? 255 - (4 * u + jo) : 4 * u + jo;
  // precompute ep = 2^(8*aw) fp32 for OWN row (wave-internal, no barrier)
  #pragma unroll
  for (int i = 0; i < 4; ++i) {
    int tc = lane + i * 64;
    epsh[a][tc] = __builtin_amdgcn_exp2f(8.0f * bf2f(awsh[a][tc]));
  }
  // t-loop (R20 body): 2x b64 kv + broadcast ep/aw; 1 native exp/iter
  size_t rowbase = ((size_t)h * 256 + s) * 256;
  float cd2 = (SCALE * LOG2E) * QKV[(size_t)s * 2048 + h * 64 + lane];
  float S1 = 0.f, S2 = 0.f, S3p = 0.f, Sp = 0.f, P2p = 0.f, AVp = 0.f;
  const uint32_t* kvrow = &kvT[lane * 258];
  const ushort* awrow = awsh[a];
  const float* eprow = epsh[a];
  const int nt4 = (s + 4) & ~3;        // s+1 rounded up to mult of 4
  #pragma unroll 2
  for (int tb = 0; tb < nt4; tb += 4) {
    uint2 kvA = *reinterpret_cast<const uint2*>(&kvrow[tb]);
    uint2 kvB = *reinterpret_cast<const uint2*>(&kvrow[tb + 2]);
    float4 ep4 = *reinterpret_cast<const float4*>(&eprow[tb]);
    ushort4 aw4 = *reinterpret_cast<const ushort4*>(&awrow[tb]);
    uint32_t kvj[4] = {kvA.x, kvA.y, kvB.x, kvB.y};
    ushort awj[4] = {aw4.x, aw4.y, aw4.z, aw4.w};
    float epj[4] = {ep4.x, ep4.y, ep4.z, ep4.w};
    #pragma unroll
    for (int j = 0; j < 4; ++j) {
      float kf = __uint_as_float(kvj[j] << 16);
      float vf = __uint_as_float(kvj[j] & 0xFFFF0000u);
      float aw = bf2f(awj[j]);
      float e  = __builtin_amdgcn_exp2f(fmaf(-cd2, kf, aw));
      float ep = epj[j];
      S1 += e;
      S2  = fmaf(e, e, S2);
      S3p = fmaf(e, ep, S3p);
      Sp += ep;
      P2p = fmaf(ep, ep, P2p);
      AVp = fmaf(ep, vf, AVp);
    }
  }
  float invS1 = 1.f / S1;
  float invSp = 1.f / Sp;
  float qk = S2 * invS1 * invS1 - 2.f * S3p * invS1 * invSp + P2p * invSp * invSp;
  float av = AVp * invSp;
  attn_out[(size_t)s * 1024 + h * 64 + lane] = av;
  #pragma unroll
  for (int i = 0; i < 4; ++i) {
    int tc = lane + i * 64;
    pOut[rowbase + tc] = eprow[tc] * invSp;   // masked -> ep=0 -> p=0
  }
  qkpart[((size_t)h * 256 + s) * 64 + lane] = qk;
}

// ---------------------------------------------------------------------------
// GEMM 2 + tail in ONE dispatch. Blocks 0..255: 32x32-tile FULL-K bf16 MFMA,
// direct write to out. Blocks 256..263: qk (sum 256 rows) / v/o importance
// (sum |attn_out|). grid = 264, block = 256.  (verified R22)
// ---------------------------------------------------------------------------
__global__ __launch_bounds__(256) void gemm_o_tail_kernel(
    const float* __restrict__ A, const float* __restrict__ W,
    const float* __restrict__ qkpart, float* __restrict__ out,
    float* __restrict__ qkout, float* __restrict__ vout,
    float* __restrict__ oout) {
  __shared__ ushort As[2048];   // 32 rows x 64 k bf16, XOR swizzle
  __shared__ ushort Bs[2048];   // 32 n    x 64 k
  char* Asc = (char*)As;
  char* Bsc = (char*)Bs;
  const int b = blockIdx.x, t = threadIdx.x;
  if (b < 256) {
    const int tm = b >> 5, tn = b & 31;       // 8 m x 32 n tiles
    const int m0 = tm * 32, n0 = tn * 32;
    const int arow = t >> 3, aslot = t & 7;   // A: 32 rows x 16 slots
    const int kp = t >> 3, ng = t & 7;        // B: 32 kpairs x 8 ngroups
    float4 ra[2], rb0, rb1;
    auto LOAD = [&](int k0) {
      #pragma unroll
      for (int i = 0; i < 2; ++i)
        ra[i] = *reinterpret_cast<const float4*>(A + (size_t)(m0 + arow) * 1024 + k0 + (aslot + 8 * i) * 4);
      rb0 = *reinterpret_cast<const float4*>(W + (size_t)(k0 + 2 * kp) * 1024 + n0 + ng * 4);
      rb1 = *reinterpret_cast<const float4*>(W + (size_t)(k0 + 2 * kp + 1) * 1024 + n0 + ng * 4);
    };
    LOAD(0);
    const int wid = t >> 6, qm = wid >> 1, qn = wid & 1, lane = t & 63;
    const int lr = lane & 15, lk = lane >> 4;
    const int sw = (lr & 7) << 4;
    floatx4 acc = (floatx4){0.f, 0.f, 0.f, 0.f};
    for (int kt = 0; kt < 16; ++kt) {
      #pragma unroll
      for (int i = 0; i < 2; ++i) {
        int c = (aslot + 8 * i) * 4;
        ushort4 wv;
        wv.x = f2bf(ra[i].x); wv.y = f2bf(ra[i].y); wv.z = f2bf(ra[i].z); wv.w = f2bf(ra[i].w);
        *reinterpret_cast<ushort4*>(Asc + arow * 128 + ((c * 2) ^ ((arow & 7) << 4))) = wv;
      }
      {
        const float* p0 = (const float*)&rb0;
        const float* p1 = (const float*)&rb1;
        #pragma unroll
        for (int j = 0; j < 4; ++j) {
          int n = ng * 4 + j;
          uint32_t v = (uint32_t)f2bf(p0[j]) | ((uint32_t)f2bf(p1[j]) << 16);
          *reinterpret_cast<uint32_t*>(Bsc + n * 128 + ((kp * 4) ^ ((n & 7) << 4))) = v;
        }
      }
      __syncthreads();
      if (kt + 1 < 16) LOAD(64 * (kt + 1));
      #pragma unroll
      for (int kc = 0; kc < 2; ++kc) {
        short8 af = *reinterpret_cast<const short8*>(
            Asc + (qm * 16 + lr) * 128 + ((kc * 64 + lk * 16) ^ sw));
        short8 bf = *reinterpret_cast<const short8*>(
            Bsc + (qn * 16 + lr) * 128 + ((kc * 64 + lk * 16) ^ sw));
        acc = __builtin_amdgcn_mfma_f32_16x16x32_bf16(af, bf, acc, 0, 0, 0);
      }
      __syncthreads();
    }
    #pragma unroll
    for (int r = 0; r < 4; ++r) {
      int row = m0 + qm * 16 + lk * 4 + r;
      int col = n0 + qn * 16 + lr;
      out[(size_t)row * 1024 + col] = acc[r];
    }
  } else {
    int idx = (b - 256) * 256 + t;            // 0..2047
    if (idx < 1024) {
      int h = idx >> 6, d = idx & 63;
      float sum = 0.f;
      for (int j = 0; j < 256; ++j) sum += qkpart[((size_t)h * 256 + j) * 64 + d];
      qkout[idx] = sum;
    } else {
      int c = idx - 1024;
      float sum = 0.f;
      for (int s = 0; s < 256; ++s) sum += fabsf(A[(size_t)s * 1024 + c]);
      vout[c] = sum;
      oout[c] = sum;
    }
  }
}

// ---------------------------------------------------------------------------
extern "C" void kernel_launch(void* const* d_in, const int* in_sizes, int n_in,
                              void* d_out, int out_size, void* d_ws, size_t ws_size,
                              hipStream_t stream) {
  const float* X    = (const float*)d_in[0];   // hidden_states (1,256,1024)
  const float* cosp = (const float*)d_in[1];   // (1,256,64)
  const float* sinp = (const float*)d_in[2];   // (1,256,64)
  // d_in[3] attention_mask: causal, implemented analytically
  const float* Wq   = (const float*)d_in[4];   // (1024,1024)
  const float* Wk   = (const float*)d_in[5];   // (1024,512)
  const float* Wv   = (const float*)d_in[6];   // (1024,512)
  const float* Wo   = (const float*)d_in[7];   // (1024,1024)

  float* out  = (float*)d_out;                 // 262144
  float* pOut = out + 262144;                  // 1048576
  float* qki  = pOut + 1048576;                // 1024
  float* vi   = qki + 1024;                    // 1024
  float* oi   = vi + 1024;                     // 1024

  float* ws       = (float*)d_ws;
  float* QKV      = ws;                        // 524288 (s-major, 2048 cols: q|k|v)
  float* attn_out = ws + 524288;               // 262144
  float* qkpart   = ws + 786432;               // 262144 (per-row qk)
  float* scratch  = ws + 1048576;              // 2097152 (QKV partials x4)

  hipLaunchKernelGGL(gemm_qkv_kernel, dim3(512), dim3(256), 0, stream, X, Wq, Wk, Wv, scratch);
  hipLaunchKernelGGL(rope_reduce_kernel, dim3(1280), dim3(256), 0, stream, scratch, QKV, cosp, sinp);
  hipLaunchKernelGGL(pdiff_fused_kernel, dim3(256), dim3(1024), 0, stream, QKV, pOut, qkpart, attn_out);
  hipLaunchKernelGGL(gemm_o_tail_kernel, dim3(264), dim3(256), 0, stream, attn_out, Wo, qkpart, out, qki, vi, oi);
}

// Round 24
// 40.934 us; speedup vs baseline: 1.2909x; 1.0533x over previous
//
#include <hip/hip_runtime.h>
#include <math.h>

// Problem constants: B=1, S=256, HID=1024, H=16, KV=8, D=64, N_REP=2
#define SCALE 0.125f   // 1/sqrt(64)
#define LOG2E 1.44269504088896340736f

typedef short short8 __attribute__((ext_vector_type(8)));
typedef float floatx4 __attribute__((ext_vector_type(4)));

static __device__ __forceinline__ ushort f2bf(float x) {
  uint32_t b = __float_as_uint(x);
  uint32_t r = (b + 0x7FFFu + ((b >> 16) & 1u)) >> 16;   // RNE
  return (ushort)r;
}
static __device__ __forceinline__ float bf2f(ushort u) {
  return __uint_as_float(((uint32_t)u) << 16);
}

// ---------------------------------------------------------------------------
// MFMA bf16 GEMM 1: X(256x1024) @ [Wq|Wk|Wv](1024x2048) -> QKV partials.
// K-split 4. grid = 512 (4 ksplit * 128 tiles), block = 256. (verified R8/R13)
// ---------------------------------------------------------------------------
__global__ __launch_bounds__(256) void gemm_qkv_kernel(
    const float* __restrict__ X, const float* __restrict__ Wq,
    const float* __restrict__ Wk, const float* __restrict__ Wv,
    float* __restrict__ Cp) {
  __shared__ ushort As[4096];
  __shared__ ushort Bs[4096];
  char* Asc = (char*)As;
  char* Bsc = (char*)Bs;
  const int bx = blockIdx.x;
  const int ks = bx >> 7;            // 0..3
  const int tile = bx & 127;         // 4 m-tiles x 32 n-tiles
  const int tile_n = tile & 31, tile_m = tile >> 5;
  const int n0 = tile_n * 64, m0 = tile_m * 64;
  const float* Bp; int ldb, bc0;
  if (n0 < 1024)      { Bp = Wq; ldb = 1024; bc0 = n0; }
  else if (n0 < 1536) { Bp = Wk; ldb = 512;  bc0 = n0 - 1024; }
  else                { Bp = Wv; ldb = 512;  bc0 = n0 - 1536; }
  const int t = threadIdx.x;
  const int arow = t >> 4, acg = t & 15;
  const int bng = t & 15;
  const int kbeg = ks * 256;
  float4 ra[4], rb0[2], rb1[2];
  auto LOAD = [&](int k0) {
    #pragma unroll
    for (int i = 0; i < 4; ++i)
      ra[i] = *reinterpret_cast<const float4*>(X + (size_t)(m0 + arow + 16 * i) * 1024 + k0 + acg * 4);
    #pragma unroll
    for (int i = 0; i < 2; ++i) {
      int k = 2 * ((t >> 4) + 16 * i);
      rb0[i] = *reinterpret_cast<const float4*>(Bp + (size_t)(k0 + k) * ldb + bc0 + bng * 4);
      rb1[i] = *reinterpret_cast<const float4*>(Bp + (size_t)(k0 + k + 1) * ldb + bc0 + bng * 4);
    }
  };
  LOAD(kbeg);
  const int wid = t >> 6, wr = wid >> 1, wc = wid & 1, lane = t & 63;
  const int lr = lane & 15, lk = lane >> 4;
  const int sw = (lr & 7) << 4;
  floatx4 acc[2][2];
  #pragma unroll
  for (int mt = 0; mt < 2; ++mt)
    #pragma unroll
    for (int nt = 0; nt < 2; ++nt)
      acc[mt][nt] = (floatx4){0.f, 0.f, 0.f, 0.f};
  for (int kt = 0; kt < 4; ++kt) {
    #pragma unroll
    for (int i = 0; i < 4; ++i) {
      int row = arow + 16 * i;
      ushort4 w;
      w.x = f2bf(ra[i].x); w.y = f2bf(ra[i].y); w.z = f2bf(ra[i].z); w.w = f2bf(ra[i].w);
      *reinterpret_cast<ushort4*>(Asc + row * 128 + ((acg * 8) ^ ((row & 7) << 4))) = w;
    }
    #pragma unroll
    for (int i = 0; i < 2; ++i) {
      int k = 2 * ((t >> 4) + 16 * i);
      const float* p0 = (const float*)&rb0[i];
      const float* p1 = (const float*)&rb1[i];
      #pragma unroll
      for (int j = 0; j < 4; ++j) {
        int n = bng * 4 + j;
        uint32_t v = (uint32_t)f2bf(p0[j]) | ((uint32_t)f2bf(p1[j]) << 16);
        *reinterpret_cast<uint32_t*>(Bsc + n * 128 + ((k * 2) ^ ((n & 7) << 4))) = v;
      }
    }
    __syncthreads();
    if (kt + 1 < 4) LOAD(kbeg + 64 * (kt + 1));
    #pragma unroll
    for (int kc = 0; kc < 2; ++kc) {
      short8 af[2], bf[2];
      #pragma unroll
      for (int mt = 0; mt < 2; ++mt)
        af[mt] = *reinterpret_cast<const short8*>(
            Asc + (wr * 32 + mt * 16 + lr) * 128 + ((kc * 64 + lk * 16) ^ sw));
      #pragma unroll
      for (int nt = 0; nt < 2; ++nt)
        bf[nt] = *reinterpret_cast<const short8*>(
            Bsc + (wc * 32 + nt * 16 + lr) * 128 + ((kc * 64 + lk * 16) ^ sw));
      #pragma unroll
      for (int mt = 0; mt < 2; ++mt)
        #pragma unroll
        for (int nt = 0; nt < 2; ++nt)
          acc[mt][nt] = __builtin_amdgcn_mfma_f32_16x16x32_bf16(af[mt], bf[nt], acc[mt][nt], 0, 0, 0);
    }
    __syncthreads();
  }
  float* Co = Cp + (size_t)ks * 524288;
  #pragma unroll
  for (int mt = 0; mt < 2; ++mt)
    #pragma unroll
    for (int nt = 0; nt < 2; ++nt)
      #pragma unroll
      for (int r = 0; r < 4; ++r) {
        int row = wr * 32 + mt * 16 + lk * 4 + r;
        int col = wc * 32 + nt * 16 + lr;
        Co[(size_t)(m0 + row) * 2048 + n0 + col] = acc[mt][nt][r];
      }
}

// ---------------------------------------------------------------------------
// Reduce the 4 QKV partials + RoPE on q/k heads. grid = 1280, block = 256.
// ---------------------------------------------------------------------------
__global__ __launch_bounds__(256) void rope_reduce_kernel(
    const float* __restrict__ Cp, float* __restrict__ QKV,
    const float* __restrict__ cs, const float* __restrict__ sn) {
  int idx = blockIdx.x * 256 + threadIdx.x;
  const float* P0 = Cp;
  const float* P1 = Cp + 524288;
  const float* P2p = Cp + 1048576;
  const float* P3 = Cp + 1572864;
  if (idx < 196608) {                 // 256 s * 24 heads * 32 pairs
    int dp = idx & 31;
    int head = (idx >> 5) % 24;       // 0..15 q heads, 16..23 k heads
    int s = idx / 768;
    int base = s * 2048 + head * 64;
    int a1 = base + dp, a2 = base + dp + 32;
    float x1 = P0[a1] + P1[a1] + P2p[a1] + P3[a1];
    float x2 = P0[a2] + P1[a2] + P2p[a2] + P3[a2];
    float c1 = cs[s * 64 + dp],      s1v = sn[s * 64 + dp];
    float c2 = cs[s * 64 + dp + 32], s2v = sn[s * 64 + dp + 32];
    QKV[a1] = x1 * c1 - x2 * s1v;   // q' = q*cos + rot_half(q)*sin
    QKV[a2] = x2 * c2 + x1 * s2v;
  } else {
    int i2 = idx - 196608;            // 131072 v elements
    int s = i2 >> 9, c = 1536 + (i2 & 511);
    int a = s * 2048 + c;
    QKV[a] = P0[a] + P1[a] + P2p[a] + P3[a];
  }
}

// ---------------------------------------------------------------------------
// FUSED QK^T + softmax + p_diff + PV, v7: ISSUE-SLOT DIET.
// R23 evidence (TLP x2 = exactly 0 delta): pdiff is issue-slot-bound; only
// instruction count matters. Changes: (1) Sp/P2 hoisted out of the loop
// (lane-invariant; per-row shuffle reduce); invSp folded into stored row ->
// epsh holds NORMALIZED p (fp32), pOut written pre-loop; loop has 4 chains
// (S1,S2,S3=sum e*p, AV=sum p*v). (2) awsh bf16->fp32: no per-iter unpack.
// ~11 issue slots/iter vs ~14. LDS 131KB, grid 256, block 1024 (R23 config).
// ---------------------------------------------------------------------------
__global__ __launch_bounds__(1024) void pdiff_fused_kernel(
    const float* __restrict__ QKV, float* __restrict__ pOut,
    float* __restrict__ qkpart, float* __restrict__ attn_out) {
  __shared__ ushort ksh[16384];       // 32KB swizzled [t][d] bf16 (MFMA B)
  __shared__ uint32_t kvT[64 * 258];  // 64.5KB transposed [d][t]: k lo | v hi
  __shared__ ushort qsh[1024];        // 2KB  swizzled [a][d] bf16 (16 rows)
  __shared__ float awsh[16][260];     // 16.25KB fp32 (scale^2*log2e*qk, masked)
  __shared__ float epsh[16][260];     // 16.25KB fp32 normalized p per row
  char* kshc = (char*)ksh;
  char* qshc = (char*)qsh;
  const int g = blockIdx.x >> 5;
  const int u = blockIdx.x & 31;
  const int t = threadIdx.x;
  // stage k (swizzled, for MFMA) + kvT (transposed packed, for t-loop)
  #pragma unroll
  for (int i = 0; i < 4; ++i) {
    int fi = t + i * 1024;             // 4096 float4 slots
    int tt = fi >> 4, c = (fi & 15) * 4;
    float4 kv = *reinterpret_cast<const float4*>(QKV + (size_t)tt * 2048 + 1024 + g * 64 + c);
    float4 vv = *reinterpret_cast<const float4*>(QKV + (size_t)tt * 2048 + 1536 + g * 64 + c);
    ushort4 wk;
    wk.x = f2bf(kv.x); wk.y = f2bf(kv.y); wk.z = f2bf(kv.z); wk.w = f2bf(kv.w);
    *reinterpret_cast<ushort4*>(kshc + tt * 128 + ((c * 2) ^ ((tt & 7) << 4))) = wk;
    kvT[(c + 0) * 258 + tt] = (uint32_t)wk.x | ((uint32_t)f2bf(vv.x) << 16);
    kvT[(c + 1) * 258 + tt] = (uint32_t)wk.y | ((uint32_t)f2bf(vv.y) << 16);
    kvT[(c + 2) * 258 + tt] = (uint32_t)wk.z | ((uint32_t)f2bf(vv.z) << 16);
    kvT[(c + 3) * 258 + tt] = (uint32_t)wk.w | ((uint32_t)f2bf(vv.w) << 16);
  }
  if (t < 512) { // stage the 16 q rows: a = pr*8 + mr*4 + jo
    int a = t >> 5;                    // 0..15
    int c = (t & 31) * 2;              // 0..62
    int pr = a >> 3, mr = (a >> 2) & 1, jo = a & 3;
    int s = mr ? 255 - (4 * u + jo) : 4 * u + jo;
    int hh = 2 * g + pr;
    float2 qv = *reinterpret_cast<const float2*>(QKV + (size_t)s * 2048 + hh * 64 + c);
    uint32_t pk = (uint32_t)f2bf(qv.x) | ((uint32_t)f2bf(qv.y) << 16);
    *reinterpret_cast<uint32_t*>(qshc + a * 128 + ((c * 2) ^ ((a & 7) << 4))) = pk;
  }
  __syncthreads();
  const int w = t >> 6, lane = t & 63;
  const int lr = lane & 15, lk = lane >> 4;
  const int sw = (lr & 7) << 4;
  const float AWS = SCALE * SCALE * LOG2E;
  // QK^T: 16 col-tiles, ONE per wave; awsh fp32 with causal mask baked in
  {
    int nt = w;
    floatx4 acc = (floatx4){0.f, 0.f, 0.f, 0.f};
    #pragma unroll
    for (int kc = 0; kc < 2; ++kc) {
      short8 af = *reinterpret_cast<const short8*>(
          qshc + lr * 128 + ((kc * 64 + lk * 16) ^ sw));
      int tt = nt * 16 + lr;
      short8 bf = *reinterpret_cast<const short8*>(
          kshc + tt * 128 + ((kc * 64 + lk * 16) ^ ((tt & 7) << 4)));
      acc = __builtin_amdgcn_mfma_f32_16x16x32_bf16(af, bf, acc, 0, 0, 0);
    }
    #pragma unroll
    for (int r = 0; r < 4; ++r) {
      int a = lk * 4 + r;
      int pr = a >> 3, mr = (a >> 2) & 1, jo = a & 3;
      int sa = mr ? 255 - (4 * u + jo) : 4 * u + jo;
      int tc = nt * 16 + lr;
      awsh[a][tc] = (tc <= sa) ? acc[r] * AWS : -1000.0f;
    }
  }
  __syncthreads();
  // wave w owns row a = w
  const int a = w;
  const int pr = a >> 3, mr = (a >> 2) & 1, jo = a & 3;
  const int h = 2 * g + pr;
  const int s = mr ? 255 - (4 * u + jo) : 4 * u + jo;
  size_t rowbase = ((size_t)h * 256 + s) * 256;
  // pre-loop: ep = 2^(8*aw); Sp shuffle-reduce; store NORMALIZED p (fp32)
  float epv[4], sp = 0.f;
  #pragma unroll
  for (int i = 0; i < 4; ++i) {
    epv[i] = __builtin_amdgcn_exp2f(8.0f * awsh[a][lane + i * 64]);
    sp += epv[i];
  }
  #pragma unroll
  for (int off = 32; off; off >>= 1) sp += __shfl_xor(sp, off);
  float invSp = 1.f / sp;
  float p2 = 0.f;
  #pragma unroll
  for (int i = 0; i < 4; ++i) {
    int tc = lane + i * 64;
    float pv = epv[i] * invSp;
    epsh[a][tc] = pv;
    pOut[rowbase + tc] = pv;                 // masked -> ep=0 -> p=0
    p2 = fmaf(pv, pv, p2);
  }
  #pragma unroll
  for (int off = 32; off; off >>= 1) p2 += __shfl_xor(p2, off);
  // slim t-loop: 4 chains (S1, S2, S3=sum e*p, AV=sum p*v)
  float cd2 = (SCALE * LOG2E) * QKV[(size_t)s * 2048 + h * 64 + lane];
  float S1 = 0.f, S2 = 0.f, S3 = 0.f, AV = 0.f;
  const uint32_t* kvrow = &kvT[lane * 258];
  const float* awrow = awsh[a];
  const float* prow = epsh[a];
  const int nt4 = (s + 4) & ~3;        // masked region contributes exact 0
  #pragma unroll 2
  for (int tb = 0; tb < nt4; tb += 4) {
    uint2 kvA = *reinterpret_cast<const uint2*>(&kvrow[tb]);
    uint2 kvB = *reinterpret_cast<const uint2*>(&kvrow[tb + 2]);
    float4 aw4 = *reinterpret_cast<const float4*>(&awrow[tb]);
    float4 p4 = *reinterpret_cast<const float4*>(&prow[tb]);
    uint32_t kvj[4] = {kvA.x, kvA.y, kvB.x, kvB.y};
    float awj[4] = {aw4.x, aw4.y, aw4.z, aw4.w};
    float pj[4] = {p4.x, p4.y, p4.z, p4.w};
    #pragma unroll
    for (int j = 0; j < 4; ++j) {
      float kf = __uint_as_float(kvj[j] << 16);
      float vf = __uint_as_float(kvj[j] & 0xFFFF0000u);
      float e = __builtin_amdgcn_exp2f(fmaf(-cd2, kf, awj[j]));
      S1 += e;
      S2 = fmaf(e, e, S2);
      S3 = fmaf(e, pj[j], S3);
      AV = fmaf(pj[j], vf, AV);
    }
  }
  float invS1 = 1.f / S1;
  float qk = S2 * invS1 * invS1 - 2.f * S3 * invS1 + p2;
  attn_out[(size_t)s * 1024 + h * 64 + lane] = AV;
  qkpart[((size_t)h * 256 + s) * 64 + lane] = qk;
}

// ---------------------------------------------------------------------------
// GEMM 2 + tail in ONE dispatch. Blocks 0..255: 32x32-tile FULL-K bf16 MFMA,
// direct write to out. Blocks 256..263: qk (sum 256 rows) / v/o importance
// (sum |attn_out|). grid = 264, block = 256.  (verified R22/R23)
// ---------------------------------------------------------------------------
__global__ __launch_bounds__(256) void gemm_o_tail_kernel(
    const float* __restrict__ A, const float* __restrict__ W,
    const float* __restrict__ qkpart, float* __restrict__ out,
    float* __restrict__ qkout, float* __restrict__ vout,
    float* __restrict__ oout) {
  __shared__ ushort As[2048];   // 32 rows x 64 k bf16, XOR swizzle
  __shared__ ushort Bs[2048];   // 32 n    x 64 k
  char* Asc = (char*)As;
  char* Bsc = (char*)Bs;
  const int b = blockIdx.x, t = threadIdx.x;
  if (b < 256) {
    const int tm = b >> 5, tn = b & 31;       // 8 m x 32 n tiles
    const int m0 = tm * 32, n0 = tn * 32;
    const int arow = t >> 3, aslot = t & 7;   // A: 32 rows x 16 slots
    const int kp = t >> 3, ng = t & 7;        // B: 32 kpairs x 8 ngroups
    float4 ra[2], rb0, rb1;
    auto LOAD = [&](int k0) {
      #pragma unroll
      for (int i = 0; i < 2; ++i)
        ra[i] = *reinterpret_cast<const float4*>(A + (size_t)(m0 + arow) * 1024 + k0 + (aslot + 8 * i) * 4);
      rb0 = *reinterpret_cast<const float4*>(W + (size_t)(k0 + 2 * kp) * 1024 + n0 + ng * 4);
      rb1 = *reinterpret_cast<const float4*>(W + (size_t)(k0 + 2 * kp + 1) * 1024 + n0 + ng * 4);
    };
    LOAD(0);
    const int wid = t >> 6, qm = wid >> 1, qn = wid & 1, lane = t & 63;
    const int lr = lane & 15, lk = lane >> 4;
    const int sw = (lr & 7) << 4;
    floatx4 acc = (floatx4){0.f, 0.f, 0.f, 0.f};
    for (int kt = 0; kt < 16; ++kt) {
      #pragma unroll
      for (int i = 0; i < 2; ++i) {
        int c = (aslot + 8 * i) * 4;
        ushort4 wv;
        wv.x = f2bf(ra[i].x); wv.y = f2bf(ra[i].y); wv.z = f2bf(ra[i].z); wv.w = f2bf(ra[i].w);
        *reinterpret_cast<ushort4*>(Asc + arow * 128 + ((c * 2) ^ ((arow & 7) << 4))) = wv;
      }
      {
        const float* p0 = (const float*)&rb0;
        const float* p1 = (const float*)&rb1;
        #pragma unroll
        for (int j = 0; j < 4; ++j) {
          int n = ng * 4 + j;
          uint32_t v = (uint32_t)f2bf(p0[j]) | ((uint32_t)f2bf(p1[j]) << 16);
          *reinterpret_cast<uint32_t*>(Bsc + n * 128 + ((kp * 4) ^ ((n & 7) << 4))) = v;
        }
      }
      __syncthreads();
      if (kt + 1 < 16) LOAD(64 * (kt + 1));
      #pragma unroll
      for (int kc = 0; kc < 2; ++kc) {
        short8 af = *reinterpret_cast<const short8*>(
            Asc + (qm * 16 + lr) * 128 + ((kc * 64 + lk * 16) ^ sw));
        short8 bf = *reinterpret_cast<const short8*>(
            Bsc + (qn * 16 + lr) * 128 + ((kc * 64 + lk * 16) ^ sw));
        acc = __builtin_amdgcn_mfma_f32_16x16x32_bf16(af, bf, acc, 0, 0, 0);
      }
      __syncthreads();
    }
    #pragma unroll
    for (int r = 0; r < 4; ++r) {
      int row = m0 + qm * 16 + lk * 4 + r;
      int col = n0 + qn * 16 + lr;
      out[(size_t)row * 1024 + col] = acc[r];
    }
  } else {
    int idx = (b - 256) * 256 + t;            // 0..2047
    if (idx < 1024) {
      int h = idx >> 6, d = idx & 63;
      float sum = 0.f;
      for (int j = 0; j < 256; ++j) sum += qkpart[((size_t)h * 256 + j) * 64 + d];
      qkout[idx] = sum;
    } else {
      int c = idx - 1024;
      float sum = 0.f;
      for (int s = 0; s < 256; ++s) sum += fabsf(A[(size_t)s * 1024 + c]);
      vout[c] = sum;
      oout[c] = sum;
    }
  }
}

// ---------------------------------------------------------------------------
extern "C" void kernel_launch(void* const* d_in, const int* in_sizes, int n_in,
                              void* d_out, int out_size, void* d_ws, size_t ws_size,
                              hipStream_t stream) {
  const float* X    = (const float*)d_in[0];   // hidden_states (1,256,1024)
  const float* cosp = (const float*)d_in[1];   // (1,256,64)
  const float* sinp = (const float*)d_in[2];   // (1,256,64)
  // d_in[3] attention_mask: causal, implemented analytically
  const float* Wq   = (const float*)d_in[4];   // (1024,1024)
  const float* Wk   = (const float*)d_in[5];   // (1024,512)
  const float* Wv   = (const float*)d_in[6];   // (1024,512)
  const float* Wo   = (const float*)d_in[7];   // (1024,1024)

  float* out  = (float*)d_out;                 // 262144
  float* pOut = out + 262144;                  // 1048576
  float* qki  = pOut + 1048576;                // 1024
  float* vi   = qki + 1024;                    // 1024
  float* oi   = vi + 1024;                     // 1024

  float* ws       = (float*)d_ws;
  float* QKV      = ws;                        // 524288 (s-major, 2048 cols: q|k|v)
  float* attn_out = ws + 524288;               // 262144
  float* qkpart   = ws + 786432;               // 262144 (per-row qk)
  float* scratch  = ws + 1048576;              // 2097152 (QKV partials x4)

  hipLaunchKernelGGL(gemm_qkv_kernel, dim3(512), dim3(256), 0, stream, X, Wq, Wk, Wv, scratch);
  hipLaunchKernelGGL(rope_reduce_kernel, dim3(1280), dim3(256), 0, stream, scratch, QKV, cosp, sinp);
  hipLaunchKernelGGL(pdiff_fused_kernel, dim3(256), dim3(1024), 0, stream, QKV, pOut, qkpart, attn_out);
  hipLaunchKernelGGL(gemm_o_tail_kernel, dim3(264), dim3(256), 0, stream, attn_out, Wo, qkpart, out, qki, vi, oi);
}